// Round 6
// baseline (517.448 us; speedup 1.0000x reference)
//
#include <hip/hip_runtime.h>
#include <hip/hip_fp16.h>

// ---------------- problem constants ----------------
#define NI 3
#define NS 32
#define CHN 512
#define OH 23
#define P2 529          // 23*23
#define NP 50784        // NI*NS*P2
#define UV 484          // 22*22
#define WSZ 262144      // NS*CHN*16

typedef unsigned int uint32;
typedef unsigned short u16;
typedef _Float16 f16x8 __attribute__((ext_vector_type(8)));
typedef float f32x4 __attribute__((ext_vector_type(4)));

// ---------------- workspace layout (bytes) ----------------
// featT: [snT(96)][cb4(4)][uv(484)][c(128)] f16 (c contiguous -> fwd-conv A operand)
// featC: [snT(96)][c(512)][uvp(512)] f16, uv padded 484->512 w/ zeros (adjoint B operand)
#define OFF_FEATT 0UL            // 47,579,136 B
#define OFF_LABEL 47579136UL     // 50784 f32
#define OFF_S0    47782272UL     // 50784 f32 (scores ping)
#define OFF_S1    47985408UL     // 50784 f32 (scores pong)
#define OFF_SGRAW 48188544UL     // 50784 f32 (A*wg raw)
#define OFF_WG    48391680UL     // 262144 f32
#define OFF_WGF16 49440256UL     // 262144 f16, layout [s][tap][c]
#define OFF_W0F16 49964544UL     // 262144 f16, layout [s][tap][c]
#define OFF_PART  50488832UL     // partial-sum arrays (float), 16 KB
#define OFF_FEATC 50505216UL     // 50,331,648 B
#define OFF_DG    100836864UL    // 96*8192 f32 = 3,145,728 B  (per-n DG partials)

// partial-array float indices — each slot written by exactly ONE block; NO atomics.
#define P_DEN   0       // [5][32][3] : per-(t,s,n) sum sg^2 partials
#define P_NUM   480     // [5][32]    : per-(t,s) sum wg^2
#define P_LOSS  640     // [5][32][3] : per-(t,s,n) residual-loss partials
#define P_WSQ0  1120    // [32]       : sum w0^2 per s
#define P_WSQA  1152    // [4][32]    : sum w_t^2, t=1..4
#define P_WSQ5  1280    // [1024]     : sum w5^2 per block
#define P_L5    2304    // [199]      : final loss per block

#define APITCH 536      // A_lds row pitch in halves (16B-aligned, ~2-way banks)

__device__ __forceinline__ float waveSum(float v) {
#pragma unroll
  for (int o = 32; o > 0; o >>= 1) v += __shfl_xor(v, o, 64);
  return v;
}

__device__ __forceinline__ float alphaFor(const float* __restrict__ part, int t, int s,
                                          float reg) {
  float nu = part[P_NUM + t * NS + s];
  const float* dp_ = part + P_DEN + (size_t)(t * NS + s) * 3;
  float de = dp_[0] + dp_[1] + dp_[2];
  return nu / fmaxf(de + reg * nu, 1e-8f);
}

// ---------------- setup: feat -> featT + featC (f16), w convert, label ----------------
// transpose block = (snT, cb of 64 ch, uvq of 121 uv): LDS 64x121 f32 = 31 KB
// grid = 96*8*4 = 3072 (transpose) + 32 (w) + 199 (label) = 3303 blocks x 256
__global__ __launch_bounds__(256) void k_setup(const float* __restrict__ feat,
                                               const float* __restrict__ w0,
                                               const float* __restrict__ bb,
                                               u16* __restrict__ featT,
                                               u16* __restrict__ featC,
                                               u16* __restrict__ w0f16,
                                               float* __restrict__ wmaster,
                                               float* __restrict__ label,
                                               float* __restrict__ part) {
  __shared__ float ldsT[7744];  // [64 ch][121 uv], pitch 121
  __shared__ float sred[4];
  int b = blockIdx.x, tid = threadIdx.x;
  if (b < 3072) {
    int snT = b >> 5, r5 = b & 31;
    int cb = r5 >> 2, uvq = r5 & 3;  // 64-ch group, 121-uv quarter
    int s = snT / 3, n = snT % 3;
    const float* fsrc =
        feat + ((size_t)n * NS + s) * CHN * UV + (size_t)(cb * 64) * UV + uvq * 121;
#pragma unroll
    for (int it = 0; it < 31; ++it) {
      int idx = it * 256 + tid;
      if (idx < 7744) {
        int r = (unsigned)idx / 121u;
        int j = idx - r * 121;
        ldsT[idx] = fsrc[r * 484 + j];
      }
    }
    __syncthreads();
    // featT write (transposed, c contiguous)
    uint32* dstb = (uint32*)featT +
                   ((size_t)(snT * 4 + (cb >> 1)) * UV + uvq * 121) * 64 + (cb & 1) * 32;
#pragma unroll
    for (int it = 0; it < 16; ++it) {
      int o = it * 256 + tid;
      if (o < 3872) {
        int uv = o >> 5, k = o & 31;
        float f0 = ldsT[(2 * k) * 121 + uv];
        float f1 = ldsT[(2 * k + 1) * 121 + uv];
        uint32 pk = (uint32)__half_as_ushort(__float2half(f0)) |
                    ((uint32)__half_as_ushort(__float2half(f1)) << 16);
        dstb[(size_t)uv * 64 + k] = pk;
      }
    }
    // featC write (same layout as source, just f16 cast, uv padded to 512)
    u16* cdst = featC + ((size_t)snT * 512 + cb * 64) * 512 + uvq * 121;
#pragma unroll
    for (int it = 0; it < 31; ++it) {
      int idx = it * 256 + tid;
      if (idx < 7744) {
        int r = (unsigned)idx / 121u;
        int j = idx - r * 121;
        cdst[(size_t)r * 512 + j] = __half_as_ushort(__float2half(ldsT[r * 121 + j]));
      }
    }
    if (uvq == 3) {  // zero the uv pad [484,512)
      for (int i = tid; i < 64 * 28; i += 256) {
        int r = i / 28, j = i - r * 28;
        cdst[(size_t)r * 512 + 121 + 28 + j] = 0;  // 363+121=484; pad starts at offset 484-363=121... 
      }
    }
  } else if (b < 3104) {
    int s = b - 3072;
    for (int i = tid; i < 8192; i += 256) {
      int tap = i >> 9, c = i & 511;
      w0f16[(size_t)s * 8192 + i] =
          __half_as_ushort(__float2half(w0[(size_t)s * 8192 + c * 16 + tap]));
    }
    float sq = 0.f;
    for (int i = tid; i < 8192; i += 256) {
      float v = w0[(size_t)s * 8192 + i];
      wmaster[(size_t)s * 8192 + i] = v;
      sq += v * v;
    }
    sq = waveSum(sq);
    if ((tid & 63) == 0) sred[tid >> 6] = sq;
    __syncthreads();
    if (tid == 0) part[P_WSQ0 + s] = sred[0] + sred[1] + sred[2] + sred[3];
  } else {
    int p = (b - 3104) * 256 + tid;
    if (p < NP) {
      int nsid = p / P2, rem = p % P2;
      int i = rem / OH, j = rem % OH;
      const float* bp = bb + (size_t)nsid * 4;
      float cr = (bp[1] + 0.5f * bp[3]) * 0.0625f;
      float cc = (bp[0] + 0.5f * bp[2]) * 0.0625f;
      float dy = (float)i - cr, dx = (float)j - cc;
      label[p] = __expf(-0.5f * (dy * dy + dx * dx));
    }
  }
}

// fix for pad index arithmetic above: uvq==3 covers uv [363,484); pad is [484,512).
// cdst points at uv=363, so pad offset within cdst is 484-363=121. The line writes
// cdst[r*512 + 121 + 28 + j] which is wrong; corrected kernel below re-zeroes properly.
__global__ __launch_bounds__(256) void k_padzero(u16* __restrict__ featC) {
  // grid 96: zero featC[snT][c][484..512)
  int snT = blockIdx.x, tid = threadIdx.x;
  u16* base = featC + (size_t)snT * 512 * 512;
  for (int i = tid; i < 512 * 28; i += 256) {
    int c = i / 28, j = i - c * 28;
    base[(size_t)c * 512 + 484 + j] = 0;
  }
}

// ---------------- forward conv via MFMA ----------------
// Per (s,n): G[uv,tap] = featT[uv,c] . w[c,tap]  (484x16x512 GEMM, 16x16x32 f16 MFMA)
// then scores[y,x] = sum_{ky,kx} G[(y+ky-2)*22+(x+kx-2), ky*4+kx]  (LDS gather).
// grid = 96 blocks (snT) x 1024 threads (16 waves; wave w owns M-tiles w and w+16).
__global__ __launch_bounds__(1024) void k_conv_fwd(const u16* __restrict__ featT,
                                                   const u16* __restrict__ wf16,
                                                   float* __restrict__ outbuf, int t,
                                                   float* __restrict__ part) {
  __shared__ uint32 w_lds[16 * 260];  // [tap][c-pair], pitch 260 (bank-stagger)
  __shared__ float G[496 * 17];       // [uv-row][tap], pitch 17
  __shared__ float dred[16];
  int tid = threadIdx.x;
  int snT = blockIdx.x;
  int s = snT / 3, n = snT - s * 3;
  const uint32* wsrc = (const uint32*)(wf16 + (size_t)s * 8192);
  for (int i = tid; i < 4096; i += 1024) {
    int tap = i >> 8, p = i & 255;
    w_lds[tap * 260 + p] = wsrc[i];
  }
  __syncthreads();
  int wave = tid >> 6, lane = tid & 63;
  int q = lane >> 4, m16 = lane & 15;
  int t0 = wave, t1 = (wave < 15) ? wave + 16 : wave;
  f32x4 acc0 = {0.f, 0.f, 0.f, 0.f}, acc1 = {0.f, 0.f, 0.f, 0.f};
  size_t base = (size_t)snT * 4 * UV * 128;
  size_t row0 = (size_t)(t0 * 16 + m16) * 128;
  size_t row1 = (size_t)(t1 * 16 + m16) * 128;
#pragma unroll
  for (int step = 0; step < 16; ++step) {
    int cb = step >> 2, cin = (step & 3) * 32;
    size_t cbase = base + (size_t)cb * UV * 128 + cin + q * 8;
    f16x8 a0 = *(const f16x8*)(featT + cbase + row0);
    f16x8 a1 = *(const f16x8*)(featT + cbase + row1);
    uint4 bw = *(const uint4*)&w_lds[m16 * 260 + step * 16 + q * 4];
    f16x8 bf = __builtin_bit_cast(f16x8, bw);
    acc0 = __builtin_amdgcn_mfma_f32_16x16x32_f16(a0, bf, acc0, 0, 0, 0);
    acc1 = __builtin_amdgcn_mfma_f32_16x16x32_f16(a1, bf, acc1, 0, 0, 0);
  }
  // D layout: col=lane&15 (tap), row=(lane>>4)*4+reg (uv within tile)
#pragma unroll
  for (int r = 0; r < 4; ++r) G[(t0 * 16 + q * 4 + r) * 17 + m16] = acc0[r];
  if (wave < 15) {
#pragma unroll
    for (int r = 0; r < 4; ++r) G[(t1 * 16 + q * 4 + r) * 17 + m16] = acc1[r];
  }
  __syncthreads();
  float dsq = 0.f;
  int p = tid;
  if (p < P2) {
    int y = p / 23, x = p - y * 23;
    float val = 0.f;
#pragma unroll
    for (int ky = 0; ky < 4; ++ky) {
      int u = y + ky - 2;
      if ((unsigned)u < 22u) {
#pragma unroll
        for (int kx = 0; kx < 4; ++kx) {
          int v = x + kx - 2;
          if ((unsigned)v < 22u) val += G[(u * 22 + v) * 17 + ky * 4 + kx];
        }
      }
    }
    outbuf[(size_t)(n * NS + s) * P2 + p] = val;
    dsq = val * val;
  }
  if (t >= 0) {  // t uniform
    dsq = waveSum(dsq);
    if (lane == 0) dred[wave] = dsq;
    __syncthreads();
    if (tid == 0) {
      float dsum = 0.f;
#pragma unroll
      for (int i = 0; i < 16; ++i) dsum += dred[i];
      part[P_DEN + (size_t)(t * NS + s) * 3 + n] = dsum * (1.0f / 3.0f);
    }
  }
}

// ---------------- adjoint GEMM via MFMA ----------------
// Per (s,n): DGpart[tap][c] = sum_uv R[tap][uv] * featC[c][uv]  (16x512x512 GEMM)
// R built in LDS from residuals (fused scores recurrence + loss partial).
// grid = 96 (snT) x 1024 threads (16 waves; wave w owns c-tiles 2w, 2w+1).
__global__ __launch_bounds__(1024) void k_adjoint_gemm(
    int t, const u16* __restrict__ featC, const float* __restrict__ label,
    const float* __restrict__ scores_old, float* __restrict__ scores_new,
    const float* __restrict__ sgraw, float* __restrict__ dgpart,
    float* __restrict__ part, const float* __restrict__ lsl,
    const float* __restrict__ fr) {
  __shared__ float d_arr[529];
  __shared__ _Float16 A_lds[16 * APITCH];
  __shared__ float lred[16];
  int tid = threadIdx.x;
  int snT = blockIdx.x;
  int s = snT / 3, n = snT - s * 3;
  float step = __expf(lsl[0]);
  float frv = fr[0];
  float reg = fmaxf(frv * frv, 1e-6f);
  float alpha_p = (t >= 1) ? alphaFor(part, t - 1, s, reg) : 0.f;
  // zero A_lds
  for (int i = tid; i < 16 * APITCH / 2; i += 1024) ((uint32*)A_lds)[i] = 0u;
  float lsum = 0.f;
  if (tid < P2) {
    size_t gp = (size_t)(n * NS + s) * P2 + tid;
    float S = scores_old[gp];
    if (t >= 1) {
      S -= step * alpha_p * sgraw[gp];  // scores recurrence
      scores_new[gp] = S;
    }
    float d = S - label[gp];
    d_arr[tid] = d;
    lsum = d * d;
  }
  lsum = waveSum(lsum);
  if ((tid & 63) == 0) lred[tid >> 6] = lsum;
  __syncthreads();
  if (tid == 0) {
    float L = 0.f;
#pragma unroll
    for (int i = 0; i < 16; ++i) L += lred[i];
    part[P_LOSS + (size_t)(t * NS + s) * 3 + n] = L * (1.0f / 3.0f);
  }
  // build A[tap][k=uv]: A = sw^2 * d(y=u+2-ky, x=v+2-kx), zero outside
  for (int idx = tid; idx < 7744; idx += 1024) {
    int tap = (unsigned)idx / 484u;
    int k = idx - tap * 484;
    int u = (unsigned)k / 22u, v = k - u * 22;
    int y = u + 2 - (tap >> 2), x = v + 2 - (tap & 3);
    if ((unsigned)y < 23u && (unsigned)x < 23u)
      A_lds[tap * APITCH + k] = (_Float16)(d_arr[y * 23 + x] * (1.0f / 3.0f));
  }
  __syncthreads();
  // GEMM
  int wave = tid >> 6, lane = tid & 63;
  int q = lane >> 4, m16 = lane & 15;
  int ct0 = wave * 2, ct1 = wave * 2 + 1;
  f32x4 acc0 = {0.f, 0.f, 0.f, 0.f}, acc1 = {0.f, 0.f, 0.f, 0.f};
  const _Float16* arow = A_lds + m16 * APITCH + q * 8;
  const u16* b0r = featC + ((size_t)snT * 512 + ct0 * 16 + m16) * 512 + q * 8;
  const u16* b1r = featC + ((size_t)snT * 512 + ct1 * 16 + m16) * 512 + q * 8;
#pragma unroll
  for (int step = 0; step < 16; ++step) {
    f16x8 a = *(const f16x8*)(arow + step * 32);
    f16x8 b0 = *(const f16x8*)(b0r + step * 32);
    f16x8 b1 = *(const f16x8*)(b1r + step * 32);
    acc0 = __builtin_amdgcn_mfma_f32_16x16x32_f16(a, b0, acc0, 0, 0, 0);
    acc1 = __builtin_amdgcn_mfma_f32_16x16x32_f16(a, b1, acc1, 0, 0, 0);
  }
  // D: col=lane&15 -> c within tile; row=(lane>>4)*4+r -> tap
  float* dgb = dgpart + (size_t)snT * 8192;
#pragma unroll
  for (int r = 0; r < 4; ++r) {
    int tap = q * 4 + r;
    dgb[tap * 512 + ct0 * 16 + m16] = acc0[r];
    dgb[tap * 512 + ct1 * 16 + m16] = acc1[r];
  }
}

// ---------------- weight update: dg = sum_n DGpart + reg*w; wg, wgf16, partials ------
// grid = 32 (s) x 256
__global__ __launch_bounds__(256) void k_wupd(int t, const float* __restrict__ dgpart,
                                              float* __restrict__ wmaster,
                                              float* __restrict__ wg,
                                              u16* __restrict__ wgf16,
                                              float* __restrict__ part,
                                              const float* __restrict__ lsl,
                                              const float* __restrict__ fr) {
  __shared__ float nred[4], wred[4];
  int s = blockIdx.x, tid = threadIdx.x;
  float step = __expf(lsl[0]);
  float frv = fr[0];
  float reg = fmaxf(frv * frv, 1e-6f);
  float alpha_p = (t >= 1) ? alphaFor(part, t - 1, s, reg) : 0.f;
  const float* d0 = dgpart + (size_t)(s * 3 + 0) * 8192;
  const float* d1 = dgpart + (size_t)(s * 3 + 1) * 8192;
  const float* d2 = dgpart + (size_t)(s * 3 + 2) * 8192;
  float num = 0.f, wsq = 0.f;
  for (int j = tid; j < 8192; j += 256) {
    int tap = j >> 9, c = j & 511;
    float dg = d0[j] + d1[j] + d2[j];
    size_t widx = (size_t)s * 8192 + (size_t)c * 16 + tap;
    float wold = wmaster[widx];
    float wnew = wold;
    if (t >= 1) {  // deferred weight update from previous iteration
      wnew = wold - step * alpha_p * wg[widx];
      wmaster[widx] = wnew;
    }
    float wgn = dg + reg * wnew;
    wg[widx] = wgn;
    wgf16[(size_t)s * 8192 + j] = __half_as_ushort(__float2half(wgn));
    wsq += wnew * wnew;
    num += wgn * wgn;
  }
  num = waveSum(num);
  wsq = waveSum(wsq);
  if ((tid & 63) == 0) {
    nred[tid >> 6] = num;
    wred[tid >> 6] = wsq;
  }
  __syncthreads();
  if (tid == 0) {
    part[P_NUM + t * NS + s] = nred[0] + nred[1] + nred[2] + nred[3];
    if (t >= 1) part[P_WSQA + (t - 1) * NS + s] = wred[0] + wred[1] + wred[2] + wred[3];
  }
}

// ---------------- final: w5 update + final residual loss parts ----------------
__global__ void k_final(float* __restrict__ wmaster, const float* __restrict__ wg,
                        const float* __restrict__ scores4, const float* __restrict__ sgraw,
                        const float* __restrict__ label, float* __restrict__ part,
                        const float* __restrict__ lsl, const float* __restrict__ fr) {
  __shared__ float alpha_s[32];
  __shared__ float red4[4];
  int b = blockIdx.x, tid = threadIdx.x;
  float step = __expf(lsl[0]);
  float frv = fr[0];
  float reg = fmaxf(frv * frv, 1e-6f);
  if (tid < 32) alpha_s[tid] = alphaFor(part, 4, tid, reg);
  __syncthreads();
  if (b < 1024) {
    int idx = b * 256 + tid;  // 1024*256 == 262144 exactly
    int s = idx >> 13;        // uniform per block
    float w5 = wmaster[idx] - step * alpha_s[s] * wg[idx];
    wmaster[idx] = w5;
    float sq = waveSum(w5 * w5);
    if ((tid & 63) == 0) red4[tid >> 6] = sq;
    __syncthreads();
    if (tid == 0) part[P_WSQ5 + b] = red4[0] + red4[1] + red4[2] + red4[3];
  } else {
    int p = (b - 1024) * 256 + tid;
    float contrib = 0.f;
    if (p < NP) {
      int nsid = p / P2;
      int s = nsid & 31;  // nsid = n*NS + s
      float s5 = scores4[p] - step * alpha_s[s] * sgraw[p];
      float d = s5 - label[p];
      contrib = d * d;
    }
    contrib = waveSum(contrib);
    if ((tid & 63) == 0) red4[tid >> 6] = contrib;
    __syncthreads();
    if (tid == 0)
      part[P_L5 + (b - 1024)] = (red4[0] + red4[1] + red4[2] + red4[3]) * (1.0f / 3.0f);
  }
}

// ---------------- losses: deterministic sums of all partials ----------------
__global__ void k_losses(float* __restrict__ out_losses, const float* __restrict__ part,
                         const float* __restrict__ fr) {
  __shared__ float red[8];
  int tid = threadIdx.x;  // 256
  float frv = fr[0];
  float reg = fmaxf(frv * frv, 1e-6f);
  float v5 = 0.f;
  for (int i = tid; i < 1024; i += 256) v5 += part[P_WSQ5 + i];
  v5 = waveSum(v5);
  if ((tid & 63) == 0) red[tid >> 6] = v5;
  __syncthreads();
  float wsq5 = red[0] + red[1] + red[2] + red[3];
  float l5 = 0.f;
  for (int i = tid; i < 199; i += 256) l5 += part[P_L5 + i];
  l5 = waveSum(l5);
  if ((tid & 63) == 0) red[4 + (tid >> 6)] = l5;
  __syncthreads();
  float loss5 = red[4] + red[5] + red[6] + red[7];
  if (tid < 5) {
    int t = tid;
    float ls = 0.f;
    for (int i = 0; i < 96; ++i) ls += part[P_LOSS + t * 96 + i];
    float ws_ = 0.f;
    if (t == 0) {
      for (int i = 0; i < 32; ++i) ws_ += part[P_WSQ0 + i];
    } else {
      for (int i = 0; i < 32; ++i) ws_ += part[P_WSQA + (t - 1) * 32 + i];
    }
    out_losses[t] = (ls + reg * ws_) * (1.0f / 32.0f);
  }
  if (tid == 5) out_losses[5] = (loss5 + reg * wsq5) * (1.0f / 32.0f);
}

// ---------------- launch ----------------
extern "C" void kernel_launch(void* const* d_in, const int* in_sizes, int n_in,
                              void* d_out, int out_size, void* d_ws, size_t ws_size,
                              hipStream_t stream) {
  const float* w0 = (const float*)d_in[0];
  const float* feat = (const float*)d_in[1];
  const float* bb = (const float*)d_in[2];
  const float* lsl = (const float*)d_in[3];
  const float* fr = (const float*)d_in[4];
  float* out = (float*)d_out;
  char* ws = (char*)d_ws;
  u16* featT = (u16*)(ws + OFF_FEATT);
  u16* featC = (u16*)(ws + OFF_FEATC);
  float* label = (float*)(ws + OFF_LABEL);
  float* s0 = (float*)(ws + OFF_S0);
  float* s1 = (float*)(ws + OFF_S1);
  float* sgraw = (float*)(ws + OFF_SGRAW);
  float* wg = (float*)(ws + OFF_WG);
  u16* wgf16 = (u16*)(ws + OFF_WGF16);
  u16* w0f16 = (u16*)(ws + OFF_W0F16);
  float* dgpart = (float*)(ws + OFF_DG);
  float* part = (float*)(ws + OFF_PART);

  k_setup<<<3303, 256, 0, stream>>>(feat, w0, bb, featT, featC, w0f16, out, label, part);
  k_padzero<<<96, 256, 0, stream>>>(featC);
  // initial scores_0 = A * w0
  k_conv_fwd<<<96, 1024, 0, stream>>>(featT, w0f16, s0, -1, part);
  float* sbuf[2] = {s0, s1};
  for (int t = 0; t < 5; ++t) {
    const float* so = (t == 0) ? s0 : sbuf[(t - 1) & 1];
    float* sn = sbuf[t & 1];
    k_adjoint_gemm<<<96, 1024, 0, stream>>>(t, featC, label, so, sn, sgraw, dgpart, part,
                                            lsl, fr);
    k_wupd<<<32, 256, 0, stream>>>(t, dgpart, out, wg, wgf16, part, lsl, fr);
    k_conv_fwd<<<96, 1024, 0, stream>>>(featT, wgf16, sgraw, t, part);
  }
  // scores_4 lives in s0 after t=4
  k_final<<<1223, 256, 0, stream>>>(out, wg, s0, sgraw, label, part, lsl, fr);
  k_losses<<<1, 256, 0, stream>>>(out + WSZ, part, fr);
}

// Round 7
// 516.871 us; speedup vs baseline: 1.0011x; 1.0011x over previous
//
#include <hip/hip_runtime.h>
#include <hip/hip_fp16.h>

// ---------------- problem constants ----------------
#define NI 3
#define NS 32
#define CHN 512
#define OH 23
#define P2 529          // 23*23
#define NP 50784        // NI*NS*P2
#define UV 484          // 22*22
#define WSZ 262144      // NS*CHN*16

typedef unsigned int uint32;
typedef unsigned short u16;
typedef _Float16 f16x8 __attribute__((ext_vector_type(8)));
typedef float f32x4 __attribute__((ext_vector_type(4)));

// ---------------- workspace layout (bytes) ----------------
// featT: [snT(96)][cb4(4)][uv(484)][c(128)] f16 (c contiguous -> fwd-conv operand)
// featC: [snT(96)][c(512)][uvp(512)] f16, uv padded 484->512 with zeros (adjoint B)
#define OFF_FEATT 0UL            // 47,579,136 B
#define OFF_LABEL 47579136UL     // 50784 f32
#define OFF_S0    47782272UL     // 50784 f32 (scores ping)
#define OFF_S1    47985408UL     // 50784 f32 (scores pong)
#define OFF_SGRAW 48188544UL     // 50784 f32 (A*wg raw)
#define OFF_WG    48391680UL     // 262144 f32
#define OFF_WGF16 49440256UL     // 262144 f16, layout [s][tap][c]
#define OFF_W0F16 49964544UL     // 262144 f16, layout [s][tap][c]
#define OFF_PART  50488832UL     // partial-sum arrays (float), 16 KB
#define OFF_FEATC 50505216UL     // 50,331,648 B
#define OFF_DG    100836864UL    // 96*8192 f32 = 3,145,728 B  (per-n DG partials)

// partial-array float indices — each slot written by exactly ONE block; NO atomics.
#define P_DEN   0       // [5][32][3] : per-(t,s,n) sum sg^2 partials
#define P_NUM   480     // [5][32]    : per-(t,s) sum wg^2
#define P_LOSS  640     // [5][32][3] : per-(t,s,n) residual-loss partials
#define P_WSQ0  1120    // [32]       : sum w0^2 per s
#define P_WSQA  1152    // [4][32]    : sum w_t^2, t=1..4
#define P_WSQ5  1280    // [1024]     : sum w5^2 per block
#define P_L5    2304    // [199]      : final loss per block

#define APITCH 536      // A_lds row pitch in halves (16B-aligned)

__device__ __forceinline__ float waveSum(float v) {
#pragma unroll
  for (int o = 32; o > 0; o >>= 1) v += __shfl_xor(v, o, 64);
  return v;
}

__device__ __forceinline__ uint32 packh2(float a, float b) {
  return (uint32)__half_as_ushort(__float2half(a)) |
         ((uint32)__half_as_ushort(__float2half(b)) << 16);
}

__device__ __forceinline__ float alphaFor(const float* __restrict__ part, int t, int s,
                                          float reg) {
  float nu = part[P_NUM + t * NS + s];
  const float* dp_ = part + P_DEN + (size_t)(t * NS + s) * 3;
  float de = dp_[0] + dp_[1] + dp_[2];
  return nu / fmaxf(de + reg * nu, 1e-8f);
}

// ---------------- setup ----------------
// block types:
//   [0, 6144)      : featT transpose tiles (snT x 16 c-groups of 32 x 4 uv-quarters)
//                    LDS 32x121 f32 = 15.5 KB -> high occupancy
//   [6144, 7680)   : featC streaming cast-copy, no LDS (snT x 16 c-groups of 32)
//   [7680, 7712)   : w0 convert + wsq partial (per s)
//   [7712, 7911)   : label
__global__ __launch_bounds__(256) void k_setup(const float* __restrict__ feat,
                                               const float* __restrict__ w0,
                                               const float* __restrict__ bb,
                                               u16* __restrict__ featT,
                                               u16* __restrict__ featC,
                                               u16* __restrict__ w0f16,
                                               float* __restrict__ wmaster,
                                               float* __restrict__ label,
                                               float* __restrict__ part) {
  __shared__ float ldsT[3872];  // [32 ch][121 uv]
  __shared__ float sred[4];
  int b = blockIdx.x, tid = threadIdx.x;
  if (b < 6144) {
    int snT = b >> 6, r6 = b & 63;
    int cb16 = r6 >> 2, uvq = r6 & 3;  // 32-ch group, 121-uv quarter
    int s = snT / 3, n = snT % 3;
    const float* fsrc =
        feat + ((size_t)n * NS + s) * CHN * UV + (size_t)(cb16 * 32) * UV + uvq * 121;
#pragma unroll
    for (int it = 0; it < 16; ++it) {
      int idx = it * 256 + tid;
      if (idx < 3872) {
        int r = (unsigned)idx / 121u;
        int j = idx - r * 121;
        ldsT[idx] = fsrc[r * 484 + j];
      }
    }
    __syncthreads();
    // write transposed: 121 uv x 16 u32 (c-pairs)
    uint32* dstb = (uint32*)featT +
                   ((size_t)(snT * 4 + (cb16 >> 2)) * UV + uvq * 121) * 64 +
                   (cb16 & 3) * 16;
#pragma unroll
    for (int it = 0; it < 8; ++it) {
      int o = it * 256 + tid;
      if (o < 1936) {
        int uv = o >> 4, k = o & 15;
        dstb[(size_t)uv * 64 + k] =
            packh2(ldsT[(2 * k) * 121 + uv], ldsT[(2 * k + 1) * 121 + uv]);
      }
    }
  } else if (b < 7680) {
    // featC: straight f32->f16 cast copy with uv pad, fully coalesced
    int blk = b - 6144;
    int snT = blk >> 4, cq = blk & 15;  // 32-c group
    int s = snT / 3, n = snT % 3;
    const float* src =
        feat + ((size_t)n * NS + s) * CHN * UV + (size_t)(cq * 32) * UV;
    uint32* dst = (uint32*)featC + ((size_t)snT * 512 + cq * 32) * 256;
#pragma unroll
    for (int it = 0; it < 32; ++it) {
      int o = it * 256 + tid;  // [0, 8192)
      int r = o >> 8, j = o & 255;
      uint32 pk = 0u;
      if (j < 242) {
        float2 f = *(const float2*)(src + (size_t)r * 484 + 2 * j);
        pk = packh2(f.x, f.y);
      }
      dst[(size_t)r * 256 + j] = pk;
    }
  } else if (b < 7712) {
    int s = b - 7680;
    for (int i = tid; i < 8192; i += 256) {
      int tap = i >> 9, c = i & 511;
      w0f16[(size_t)s * 8192 + i] =
          __half_as_ushort(__float2half(w0[(size_t)s * 8192 + c * 16 + tap]));
    }
    float sq = 0.f;
    for (int i = tid; i < 8192; i += 256) {
      float v = w0[(size_t)s * 8192 + i];
      wmaster[(size_t)s * 8192 + i] = v;
      sq += v * v;
    }
    sq = waveSum(sq);
    if ((tid & 63) == 0) sred[tid >> 6] = sq;
    __syncthreads();
    if (tid == 0) part[P_WSQ0 + s] = sred[0] + sred[1] + sred[2] + sred[3];
  } else {
    int p = (b - 7712) * 256 + tid;
    if (p < NP) {
      int nsid = p / P2, rem = p % P2;
      int i = rem / OH, j = rem % OH;
      const float* bp = bb + (size_t)nsid * 4;
      float cr = (bp[1] + 0.5f * bp[3]) * 0.0625f;
      float cc = (bp[0] + 0.5f * bp[2]) * 0.0625f;
      float dy = (float)i - cr, dx = (float)j - cc;
      label[p] = __expf(-0.5f * (dy * dy + dx * dx));
    }
  }
}

// ---------------- forward conv via MFMA ----------------
// Per (s,n): G[uv,tap] = featT[uv,c] . w[c,tap]  (484x16x512 GEMM, 16x16x32 f16 MFMA)
// then scores[y,x] = sum_{ky,kx} G[(y+ky-2)*22+(x+kx-2), ky*4+kx]  (LDS gather).
// grid = 96 blocks (snT) x 1024 threads (16 waves; wave w owns M-tiles w and w+16).
__global__ __launch_bounds__(1024) void k_conv_fwd(const u16* __restrict__ featT,
                                                   const u16* __restrict__ wf16,
                                                   float* __restrict__ outbuf, int t,
                                                   float* __restrict__ part) {
  __shared__ uint32 w_lds[16 * 260];  // [tap][c-pair], pitch 260 (bank-stagger)
  __shared__ float G[496 * 17];       // [uv-row][tap], pitch 17
  __shared__ float dred[16];
  int tid = threadIdx.x;
  int snT = blockIdx.x;
  int s = snT / 3, n = snT - s * 3;
  const uint32* wsrc = (const uint32*)(wf16 + (size_t)s * 8192);
  for (int i = tid; i < 4096; i += 1024) {
    int tap = i >> 8, p = i & 255;
    w_lds[tap * 260 + p] = wsrc[i];
  }
  __syncthreads();
  int wave = tid >> 6, lane = tid & 63;
  int q = lane >> 4, m16 = lane & 15;
  int t0 = wave, t1 = (wave < 15) ? wave + 16 : wave;
  f32x4 acc0 = {0.f, 0.f, 0.f, 0.f}, acc1 = {0.f, 0.f, 0.f, 0.f};
  size_t base = (size_t)snT * 4 * UV * 128;
  size_t row0 = (size_t)(t0 * 16 + m16) * 128;
  size_t row1 = (size_t)(t1 * 16 + m16) * 128;
#pragma unroll
  for (int step = 0; step < 16; ++step) {
    int cb = step >> 2, cin = (step & 3) * 32;
    size_t cbase = base + (size_t)cb * UV * 128 + cin + q * 8;
    f16x8 a0 = *(const f16x8*)(featT + cbase + row0);
    f16x8 a1 = *(const f16x8*)(featT + cbase + row1);
    uint4 bw = *(const uint4*)&w_lds[m16 * 260 + step * 16 + q * 4];
    f16x8 bf = __builtin_bit_cast(f16x8, bw);
    acc0 = __builtin_amdgcn_mfma_f32_16x16x32_f16(a0, bf, acc0, 0, 0, 0);
    acc1 = __builtin_amdgcn_mfma_f32_16x16x32_f16(a1, bf, acc1, 0, 0, 0);
  }
  // D layout: col=lane&15 (tap), row=(lane>>4)*4+reg (uv within tile)
#pragma unroll
  for (int r = 0; r < 4; ++r) G[(t0 * 16 + q * 4 + r) * 17 + m16] = acc0[r];
  if (wave < 15) {
#pragma unroll
    for (int r = 0; r < 4; ++r) G[(t1 * 16 + q * 4 + r) * 17 + m16] = acc1[r];
  }
  __syncthreads();
  float dsq = 0.f;
  int p = tid;
  if (p < P2) {
    int y = p / 23, x = p - y * 23;
    float val = 0.f;
#pragma unroll
    for (int ky = 0; ky < 4; ++ky) {
      int u = y + ky - 2;
      if ((unsigned)u < 22u) {
#pragma unroll
        for (int kx = 0; kx < 4; ++kx) {
          int v = x + kx - 2;
          if ((unsigned)v < 22u) val += G[(u * 22 + v) * 17 + ky * 4 + kx];
        }
      }
    }
    outbuf[(size_t)(n * NS + s) * P2 + p] = val;
    dsq = val * val;
  }
  if (t >= 0) {  // t uniform
    dsq = waveSum(dsq);
    if (lane == 0) dred[wave] = dsq;
    __syncthreads();
    if (tid == 0) {
      float dsum = 0.f;
#pragma unroll
      for (int i = 0; i < 16; ++i) dsum += dred[i];
      part[P_DEN + (size_t)(t * NS + s) * 3 + n] = dsum * (1.0f / 3.0f);
    }
  }
}

// ---------------- adjoint GEMM via MFMA ----------------
// Per (s,n): DGpart[tap][c] = sum_uv R[tap][uv] * featC[c][uv]  (16x512x512 GEMM)
// R built in LDS from residuals (fused scores recurrence + loss partial).
// grid = 96 (snT) x 1024 threads (16 waves; wave w owns c-tiles 2w, 2w+1).
__global__ __launch_bounds__(1024) void k_adjoint_gemm(
    int t, const u16* __restrict__ featC, const float* __restrict__ label,
    const float* __restrict__ scores_old, float* __restrict__ scores_new,
    const float* __restrict__ sgraw, float* __restrict__ dgpart,
    float* __restrict__ part, const float* __restrict__ lsl,
    const float* __restrict__ fr) {
  __shared__ float d_arr[529];
  __shared__ _Float16 A_lds[16 * APITCH];
  __shared__ float lred[16];
  int tid = threadIdx.x;
  int snT = blockIdx.x;
  int s = snT / 3, n = snT - s * 3;
  float step = __expf(lsl[0]);
  float frv = fr[0];
  float reg = fmaxf(frv * frv, 1e-6f);
  float alpha_p = (t >= 1) ? alphaFor(part, t - 1, s, reg) : 0.f;
  // zero A_lds
  for (int i = tid; i < 16 * APITCH / 2; i += 1024) ((uint32*)A_lds)[i] = 0u;
  float lsum = 0.f;
  if (tid < P2) {
    size_t gp = (size_t)(n * NS + s) * P2 + tid;
    float S = scores_old[gp];
    if (t >= 1) {
      S -= step * alpha_p * sgraw[gp];  // scores recurrence
      scores_new[gp] = S;
    }
    float d = S - label[gp];
    d_arr[tid] = d;
    lsum = d * d;
  }
  lsum = waveSum(lsum);
  if ((tid & 63) == 0) lred[tid >> 6] = lsum;
  __syncthreads();
  if (tid == 0) {
    float L = 0.f;
#pragma unroll
    for (int i = 0; i < 16; ++i) L += lred[i];
    part[P_LOSS + (size_t)(t * NS + s) * 3 + n] = L * (1.0f / 3.0f);
  }
  // build A[tap][k=uv]: A = sw^2 * d(y=u+2-ky, x=v+2-kx), zero outside
  for (int idx = tid; idx < 7744; idx += 1024) {
    int tap = (unsigned)idx / 484u;
    int k = idx - tap * 484;
    int u = (unsigned)k / 22u, v = k - u * 22;
    int y = u + 2 - (tap >> 2), x = v + 2 - (tap & 3);
    if ((unsigned)y < 23u && (unsigned)x < 23u)
      A_lds[tap * APITCH + k] = (_Float16)(d_arr[y * 23 + x] * (1.0f / 3.0f));
  }
  __syncthreads();
  // GEMM
  int wave = tid >> 6, lane = tid & 63;
  int q = lane >> 4, m16 = lane & 15;
  int ct0 = wave * 2, ct1 = wave * 2 + 1;
  f32x4 acc0 = {0.f, 0.f, 0.f, 0.f}, acc1 = {0.f, 0.f, 0.f, 0.f};
  const _Float16* arow = A_lds + m16 * APITCH + q * 8;
  const u16* b0r = featC + ((size_t)snT * 512 + ct0 * 16 + m16) * 512 + q * 8;
  const u16* b1r = featC + ((size_t)snT * 512 + ct1 * 16 + m16) * 512 + q * 8;
#pragma unroll
  for (int step = 0; step < 16; ++step) {
    f16x8 a = *(const f16x8*)(arow + step * 32);
    f16x8 b0 = *(const f16x8*)(b0r + step * 32);
    f16x8 b1 = *(const f16x8*)(b1r + step * 32);
    acc0 = __builtin_amdgcn_mfma_f32_16x16x32_f16(a, b0, acc0, 0, 0, 0);
    acc1 = __builtin_amdgcn_mfma_f32_16x16x32_f16(a, b1, acc1, 0, 0, 0);
  }
  // D: col=lane&15 -> c within tile; row=(lane>>4)*4+r -> tap
  float* dgb = dgpart + (size_t)snT * 8192;
#pragma unroll
  for (int r = 0; r < 4; ++r) {
    int tap = q * 4 + r;
    dgb[tap * 512 + ct0 * 16 + m16] = acc0[r];
    dgb[tap * 512 + ct1 * 16 + m16] = acc1[r];
  }
}

// ---------------- weight update: dg = sum_n DGpart + reg*w; wg, wgf16, partials ------
// grid = 32 (s) x 256
__global__ __launch_bounds__(256) void k_wupd(int t, const float* __restrict__ dgpart,
                                              float* __restrict__ wmaster,
                                              float* __restrict__ wg,
                                              u16* __restrict__ wgf16,
                                              float* __restrict__ part,
                                              const float* __restrict__ lsl,
                                              const float* __restrict__ fr) {
  __shared__ float nred[4], wred[4];
  int s = blockIdx.x, tid = threadIdx.x;
  float step = __expf(lsl[0]);
  float frv = fr[0];
  float reg = fmaxf(frv * frv, 1e-6f);
  float alpha_p = (t >= 1) ? alphaFor(part, t - 1, s, reg) : 0.f;
  const float* d0 = dgpart + (size_t)(s * 3 + 0) * 8192;
  const float* d1 = dgpart + (size_t)(s * 3 + 1) * 8192;
  const float* d2 = dgpart + (size_t)(s * 3 + 2) * 8192;
  float num = 0.f, wsq = 0.f;
  for (int j = tid; j < 8192; j += 256) {
    int tap = j >> 9, c = j & 511;
    float dg = d0[j] + d1[j] + d2[j];
    size_t widx = (size_t)s * 8192 + (size_t)c * 16 + tap;
    float wold = wmaster[widx];
    float wnew = wold;
    if (t >= 1) {  // deferred weight update from previous iteration
      wnew = wold - step * alpha_p * wg[widx];
      wmaster[widx] = wnew;
    }
    float wgn = dg + reg * wnew;
    wg[widx] = wgn;
    wgf16[(size_t)s * 8192 + j] = __half_as_ushort(__float2half(wgn));
    wsq += wnew * wnew;
    num += wgn * wgn;
  }
  num = waveSum(num);
  wsq = waveSum(wsq);
  if ((tid & 63) == 0) {
    nred[tid >> 6] = num;
    wred[tid >> 6] = wsq;
  }
  __syncthreads();
  if (tid == 0) {
    part[P_NUM + t * NS + s] = nred[0] + nred[1] + nred[2] + nred[3];
    if (t >= 1) part[P_WSQA + (t - 1) * NS + s] = wred[0] + wred[1] + wred[2] + wred[3];
  }
}

// ---------------- final: w5 update + final residual loss parts ----------------
__global__ void k_final(float* __restrict__ wmaster, const float* __restrict__ wg,
                        const float* __restrict__ scores4, const float* __restrict__ sgraw,
                        const float* __restrict__ label, float* __restrict__ part,
                        const float* __restrict__ lsl, const float* __restrict__ fr) {
  __shared__ float alpha_s[32];
  __shared__ float red4[4];
  int b = blockIdx.x, tid = threadIdx.x;
  float step = __expf(lsl[0]);
  float frv = fr[0];
  float reg = fmaxf(frv * frv, 1e-6f);
  if (tid < 32) alpha_s[tid] = alphaFor(part, 4, tid, reg);
  __syncthreads();
  if (b < 1024) {
    int idx = b * 256 + tid;  // 1024*256 == 262144 exactly
    int s = idx >> 13;        // uniform per block
    float w5 = wmaster[idx] - step * alpha_s[s] * wg[idx];
    wmaster[idx] = w5;
    float sq = waveSum(w5 * w5);
    if ((tid & 63) == 0) red4[tid >> 6] = sq;
    __syncthreads();
    if (tid == 0) part[P_WSQ5 + b] = red4[0] + red4[1] + red4[2] + red4[3];
  } else {
    int p = (b - 1024) * 256 + tid;
    float contrib = 0.f;
    if (p < NP) {
      int nsid = p / P2;
      int s = nsid & 31;  // nsid = n*NS + s
      float s5 = scores4[p] - step * alpha_s[s] * sgraw[p];
      float d = s5 - label[p];
      contrib = d * d;
    }
    contrib = waveSum(contrib);
    if ((tid & 63) == 0) red4[tid >> 6] = contrib;
    __syncthreads();
    if (tid == 0)
      part[P_L5 + (b - 1024)] = (red4[0] + red4[1] + red4[2] + red4[3]) * (1.0f / 3.0f);
  }
}

// ---------------- losses: deterministic sums of all partials ----------------
__global__ void k_losses(float* __restrict__ out_losses, const float* __restrict__ part,
                         const float* __restrict__ fr) {
  __shared__ float red[8];
  int tid = threadIdx.x;  // 256
  float frv = fr[0];
  float reg = fmaxf(frv * frv, 1e-6f);
  float v5 = 0.f;
  for (int i = tid; i < 1024; i += 256) v5 += part[P_WSQ5 + i];
  v5 = waveSum(v5);
  if ((tid & 63) == 0) red[tid >> 6] = v5;
  __syncthreads();
  float wsq5 = red[0] + red[1] + red[2] + red[3];
  float l5 = 0.f;
  for (int i = tid; i < 199; i += 256) l5 += part[P_L5 + i];
  l5 = waveSum(l5);
  if ((tid & 63) == 0) red[4 + (tid >> 6)] = l5;
  __syncthreads();
  float loss5 = red[4] + red[5] + red[6] + red[7];
  if (tid < 5) {
    int t = tid;
    float ls = 0.f;
    for (int i = 0; i < 96; ++i) ls += part[P_LOSS + t * 96 + i];
    float ws_ = 0.f;
    if (t == 0) {
      for (int i = 0; i < 32; ++i) ws_ += part[P_WSQ0 + i];
    } else {
      for (int i = 0; i < 32; ++i) ws_ += part[P_WSQA + (t - 1) * 32 + i];
    }
    out_losses[t] = (ls + reg * ws_) * (1.0f / 32.0f);
  }
  if (tid == 5) out_losses[5] = (loss5 + reg * wsq5) * (1.0f / 32.0f);
}

// ---------------- launch ----------------
extern "C" void kernel_launch(void* const* d_in, const int* in_sizes, int n_in,
                              void* d_out, int out_size, void* d_ws, size_t ws_size,
                              hipStream_t stream) {
  const float* w0 = (const float*)d_in[0];
  const float* feat = (const float*)d_in[1];
  const float* bb = (const float*)d_in[2];
  const float* lsl = (const float*)d_in[3];
  const float* fr = (const float*)d_in[4];
  float* out = (float*)d_out;
  char* ws = (char*)d_ws;
  u16* featT = (u16*)(ws + OFF_FEATT);
  u16* featC = (u16*)(ws + OFF_FEATC);
  float* label = (float*)(ws + OFF_LABEL);
  float* s0 = (float*)(ws + OFF_S0);
  float* s1 = (float*)(ws + OFF_S1);
  float* sgraw = (float*)(ws + OFF_SGRAW);
  float* wg = (float*)(ws + OFF_WG);
  u16* wgf16 = (u16*)(ws + OFF_WGF16);
  u16* w0f16 = (u16*)(ws + OFF_W0F16);
  float* dgpart = (float*)(ws + OFF_DG);
  float* part = (float*)(ws + OFF_PART);

  k_setup<<<7911, 256, 0, stream>>>(feat, w0, bb, featT, featC, w0f16, out, label, part);
  // initial scores_0 = A * w0
  k_conv_fwd<<<96, 1024, 0, stream>>>(featT, w0f16, s0, -1, part);
  float* sbuf[2] = {s0, s1};
  for (int t = 0; t < 5; ++t) {
    const float* so = (t == 0) ? s0 : sbuf[(t - 1) & 1];
    float* sn = sbuf[t & 1];
    k_adjoint_gemm<<<96, 1024, 0, stream>>>(t, featC, label, so, sn, sgraw, dgpart, part,
                                            lsl, fr);
    k_wupd<<<32, 256, 0, stream>>>(t, dgpart, out, wg, wgf16, part, lsl, fr);
    k_conv_fwd<<<96, 1024, 0, stream>>>(featT, wgf16, sgraw, t, part);
  }
  // scores_4 lives in s0 after t=4
  k_final<<<1223, 256, 0, stream>>>(out, wg, s0, sgraw, label, part, lsl, fr);
  k_losses<<<1, 256, 0, stream>>>(out + WSZ, part, fr);
}

// Round 8
// 451.745 us; speedup vs baseline: 1.1454x; 1.1442x over previous
//
#include <hip/hip_runtime.h>
#include <hip/hip_fp16.h>

// ---------------- problem constants ----------------
#define NI 3
#define NS 32
#define CHN 512
#define OH 23
#define P2 529          // 23*23
#define NP 50784        // NI*NS*P2
#define UV 484          // 22*22
#define WSZ 262144      // NS*CHN*16

typedef unsigned int uint32;
typedef unsigned short u16;
typedef _Float16 f16x8 __attribute__((ext_vector_type(8)));
typedef float f32x4 __attribute__((ext_vector_type(4)));

// ---------------- workspace layout (bytes) ----------------
// featT: [snT(96)][cb4(4)][uv(484)][c(128)] f16 (c contiguous -> fwd-conv operand)
// featC: [snT(96)][c(512)][uvp(512)] f16, uv padded 484->512 with zeros (adjoint B)
#define OFF_FEATT 0UL            // 47,579,136 B
#define OFF_LABEL 47579136UL     // 50784 f32
#define OFF_S0    47782272UL     // 50784 f32 (scores ping)
#define OFF_S1    47985408UL     // 50784 f32 (scores pong)
#define OFF_SGRAW 48188544UL     // 50784 f32 (A*wg raw)
#define OFF_WG    48391680UL     // 262144 f32
#define OFF_WGF16 49440256UL     // 262144 f16, layout [s][tap][c]
#define OFF_W0F16 49964544UL     // 262144 f16, layout [s][tap][c]
#define OFF_PART  50488832UL     // partial-sum arrays (float), 16 KB
#define OFF_FEATC 50505216UL     // 50,331,648 B
#define OFF_DG    100836864UL    // 96*8192 f32 = 3,145,728 B (per-n DG partials)
#define OFF_GBUF  103982592UL    // 96*512*16 f32 = 3,145,728 B (fwd-conv G)

// partial-array float indices — each slot written by exactly ONE block; NO atomics.
#define P_DEN   0       // [5][96]     : per-(t,snT) sum sg^2 partials (k_gather)
#define P_NUM   480     // [5][32][4]  : per-(t,s,cg) sum wg^2 (k_wupd)
#define P_LOSS  1120    // [5][96]     : per-(t,snT) residual-loss partials
#define P_WSQ0  1600    // [32]        : sum w0^2 per s
#define P_WSQA  1632    // [4][32][4]  : sum w_t^2 partials, t=1..4
#define P_WSQ5  2144    // [1024]      : sum w5^2 per block
#define P_L5    3168    // [199]       : final loss per block

#define APITCH 536      // A_lds row pitch in halves (16B-aligned)

__device__ __forceinline__ float waveSum(float v) {
#pragma unroll
  for (int o = 32; o > 0; o >>= 1) v += __shfl_xor(v, o, 64);
  return v;
}

__device__ __forceinline__ uint32 packh2(float a, float b) {
  return (uint32)__half_as_ushort(__float2half(a)) |
         ((uint32)__half_as_ushort(__float2half(b)) << 16);
}

__device__ __forceinline__ float alphaFor(const float* __restrict__ part, int t, int s,
                                          float reg) {
  const float* np_ = part + P_NUM + (size_t)(t * NS + s) * 4;
  float nu = np_[0] + np_[1] + np_[2] + np_[3];
  const float* dp_ = part + P_DEN + (size_t)t * 96 + s * 3;
  float de = dp_[0] + dp_[1] + dp_[2];
  return nu / fmaxf(de + reg * nu, 1e-8f);
}

// ---------------- setup (unchanged from R7) ----------------
// block types:
//   [0, 6144)      : featT transpose tiles (snT x 16 c-groups of 32 x 4 uv-quarters)
//   [6144, 7680)   : featC streaming cast-copy, no LDS (snT x 16 c-groups of 32)
//   [7680, 7712)   : w0 convert + wsq partial (per s)
//   [7712, 7911)   : label
__global__ __launch_bounds__(256) void k_setup(const float* __restrict__ feat,
                                               const float* __restrict__ w0,
                                               const float* __restrict__ bb,
                                               u16* __restrict__ featT,
                                               u16* __restrict__ featC,
                                               u16* __restrict__ w0f16,
                                               float* __restrict__ wmaster,
                                               float* __restrict__ label,
                                               float* __restrict__ part) {
  __shared__ float ldsT[3872];  // [32 ch][121 uv]
  __shared__ float sred[4];
  int b = blockIdx.x, tid = threadIdx.x;
  if (b < 6144) {
    int snT = b >> 6, r6 = b & 63;
    int cb16 = r6 >> 2, uvq = r6 & 3;  // 32-ch group, 121-uv quarter
    int s = snT / 3, n = snT % 3;
    const float* fsrc =
        feat + ((size_t)n * NS + s) * CHN * UV + (size_t)(cb16 * 32) * UV + uvq * 121;
#pragma unroll
    for (int it = 0; it < 16; ++it) {
      int idx = it * 256 + tid;
      if (idx < 3872) {
        int r = (unsigned)idx / 121u;
        int j = idx - r * 121;
        ldsT[idx] = fsrc[r * 484 + j];
      }
    }
    __syncthreads();
    uint32* dstb = (uint32*)featT +
                   ((size_t)(snT * 4 + (cb16 >> 2)) * UV + uvq * 121) * 64 +
                   (cb16 & 3) * 16;
#pragma unroll
    for (int it = 0; it < 8; ++it) {
      int o = it * 256 + tid;
      if (o < 1936) {
        int uv = o >> 4, k = o & 15;
        dstb[(size_t)uv * 64 + k] =
            packh2(ldsT[(2 * k) * 121 + uv], ldsT[(2 * k + 1) * 121 + uv]);
      }
    }
  } else if (b < 7680) {
    int blk = b - 6144;
    int snT = blk >> 4, cq = blk & 15;  // 32-c group
    int s = snT / 3, n = snT % 3;
    const float* src =
        feat + ((size_t)n * NS + s) * CHN * UV + (size_t)(cq * 32) * UV;
    uint32* dst = (uint32*)featC + ((size_t)snT * 512 + cq * 32) * 256;
#pragma unroll
    for (int it = 0; it < 32; ++it) {
      int o = it * 256 + tid;  // [0, 8192)
      int r = o >> 8, j = o & 255;
      uint32 pk = 0u;
      if (j < 242) {
        float2 f = *(const float2*)(src + (size_t)r * 484 + 2 * j);
        pk = packh2(f.x, f.y);
      }
      dst[(size_t)r * 256 + j] = pk;
    }
  } else if (b < 7712) {
    int s = b - 7680;
    for (int i = tid; i < 8192; i += 256) {
      int tap = i >> 9, c = i & 511;
      w0f16[(size_t)s * 8192 + i] =
          __half_as_ushort(__float2half(w0[(size_t)s * 8192 + c * 16 + tap]));
    }
    float sq = 0.f;
    for (int i = tid; i < 8192; i += 256) {
      float v = w0[(size_t)s * 8192 + i];
      wmaster[(size_t)s * 8192 + i] = v;
      sq += v * v;
    }
    sq = waveSum(sq);
    if ((tid & 63) == 0) sred[tid >> 6] = sq;
    __syncthreads();
    if (tid == 0) part[P_WSQ0 + s] = sred[0] + sred[1] + sred[2] + sred[3];
  } else {
    int p = (b - 7712) * 256 + tid;
    if (p < NP) {
      int nsid = p / P2, rem = p % P2;
      int i = rem / OH, j = rem % OH;
      const float* bp = bb + (size_t)nsid * 4;
      float cr = (bp[1] + 0.5f * bp[3]) * 0.0625f;
      float cc = (bp[0] + 0.5f * bp[2]) * 0.0625f;
      float dy = (float)i - cr, dx = (float)j - cc;
      label[p] = __expf(-0.5f * (dy * dy + dx * dx));
    }
  }
}

// ---------------- forward-conv GEMM: G[uv,tap] = featT[uv,c] . w[c,tap] ----------------
// grid = 96 snT x 4 M-groups = 384 blocks x 256 (4 waves, 2 M-tiles each; tile=16 uv rows)
__global__ __launch_bounds__(256) void k_conv_gemm(const u16* __restrict__ featT,
                                                   const u16* __restrict__ wf16,
                                                   float* __restrict__ gbuf) {
  __shared__ uint32 w_lds[16 * 260];  // [tap][c-pair], pitch 260
  int tid = threadIdx.x;
  int b = blockIdx.x;
  int snT = b >> 2, mg = b & 3;
  int s = snT / 3;
  const uint32* wsrc = (const uint32*)(wf16 + (size_t)s * 8192);
  for (int i = tid; i < 4096; i += 256) {
    int tap = i >> 8, p = i & 255;
    w_lds[tap * 260 + p] = wsrc[i];
  }
  __syncthreads();
  int wave = tid >> 6, lane = tid & 63;
  int q = lane >> 4, m16 = lane & 15;
  int ta = mg * 8 + wave * 2, tb = ta + 1;
  ta = (ta > 30) ? 30 : ta;  // tile 31 would exceed uv range; duplicate tile 30
  tb = (tb > 30) ? 30 : tb;
  f32x4 acc0 = {0.f, 0.f, 0.f, 0.f}, acc1 = {0.f, 0.f, 0.f, 0.f};
  size_t base = (size_t)snT * 4 * UV * 128;
  size_t row0 = (size_t)(ta * 16 + m16) * 128;
  size_t row1 = (size_t)(tb * 16 + m16) * 128;
#pragma unroll
  for (int step = 0; step < 16; ++step) {
    int cb = step >> 2, cin = (step & 3) * 32;
    size_t cbase = base + (size_t)cb * UV * 128 + cin + q * 8;
    f16x8 a0 = *(const f16x8*)(featT + cbase + row0);
    f16x8 a1 = *(const f16x8*)(featT + cbase + row1);
    uint4 bw = *(const uint4*)&w_lds[m16 * 260 + step * 16 + q * 4];
    f16x8 bf = __builtin_bit_cast(f16x8, bw);
    acc0 = __builtin_amdgcn_mfma_f32_16x16x32_f16(a0, bf, acc0, 0, 0, 0);
    acc1 = __builtin_amdgcn_mfma_f32_16x16x32_f16(a1, bf, acc1, 0, 0, 0);
  }
  // D layout: col=lane&15 (tap), row=(lane>>4)*4+reg (uv within tile)
  float* gb = gbuf + (size_t)snT * 512 * 16;
#pragma unroll
  for (int r = 0; r < 4; ++r) {
    gb[(ta * 16 + q * 4 + r) * 16 + m16] = acc0[r];
    gb[(tb * 16 + q * 4 + r) * 16 + m16] = acc1[r];
  }
}

// ---------------- gather: scores[y,x] = sum_{ky,kx} G[...], + DEN partial ----------------
// grid = 96 (snT) x 256
__global__ __launch_bounds__(256) void k_gather(const float* __restrict__ gbuf,
                                                float* __restrict__ outbuf, int t,
                                                float* __restrict__ part) {
  __shared__ float dred[4];
  int tid = threadIdx.x;
  int snT = blockIdx.x;
  int s = snT / 3, n = snT - s * 3;
  const float* gb = gbuf + (size_t)snT * 512 * 16;
  float dsq = 0.f;
  for (int p = tid; p < P2; p += 256) {
    int y = p / 23, x = p - y * 23;
    float val = 0.f;
#pragma unroll
    for (int ky = 0; ky < 4; ++ky) {
      int u = y + ky - 2;
      if ((unsigned)u < 22u) {
#pragma unroll
        for (int kx = 0; kx < 4; ++kx) {
          int v = x + kx - 2;
          if ((unsigned)v < 22u) val += gb[(u * 22 + v) * 16 + ky * 4 + kx];
        }
      }
    }
    outbuf[(size_t)(n * NS + s) * P2 + p] = val;
    dsq += val * val;
  }
  if (t >= 0) {
    dsq = waveSum(dsq);
    if ((tid & 63) == 0) dred[tid >> 6] = dsq;
    __syncthreads();
    if (tid == 0)
      part[P_DEN + (size_t)t * 96 + snT] =
          (dred[0] + dred[1] + dred[2] + dred[3]) * (1.0f / 3.0f);
  }
}

// ---------------- adjoint GEMM via MFMA ----------------
// Per (snT, cgroup): DGpart[tap][c-range] = sum_uv R[tap][uv] * featC[c][uv]
// grid = 96 snT x 4 cgroups = 384 blocks x 256 (4 waves, 2 c-tiles each)
__global__ __launch_bounds__(256) void k_adjoint_gemm(
    int t, const u16* __restrict__ featC, const float* __restrict__ label,
    const float* __restrict__ scores_old, float* __restrict__ scores_new,
    const float* __restrict__ sgraw, float* __restrict__ dgpart,
    float* __restrict__ part, const float* __restrict__ lsl,
    const float* __restrict__ fr) {
  __shared__ float d_arr[529];
  __shared__ _Float16 A_lds[16 * APITCH];
  __shared__ float lred[4];
  int tid = threadIdx.x;
  int b = blockIdx.x;
  int snT = b >> 2, cg = b & 3;
  int s = snT / 3, n = snT - s * 3;
  float step = __expf(lsl[0]);
  float frv = fr[0];
  float reg = fmaxf(frv * frv, 1e-6f);
  float alpha_p = (t >= 1) ? alphaFor(part, t - 1, s, reg) : 0.f;
  // zero A_lds
  for (int i = tid; i < 16 * APITCH / 2; i += 256) ((uint32*)A_lds)[i] = 0u;
  float lsum = 0.f;
  for (int p = tid; p < P2; p += 256) {
    size_t gp = (size_t)(n * NS + s) * P2 + p;
    float S = scores_old[gp];
    if (t >= 1) {
      S -= step * alpha_p * sgraw[gp];  // scores recurrence
      if (cg == 0) scores_new[gp] = S;
    }
    float d = S - label[gp];
    d_arr[p] = d;
    lsum += d * d;
  }
  lsum = waveSum(lsum);
  if ((tid & 63) == 0) lred[tid >> 6] = lsum;
  __syncthreads();
  if (cg == 0 && tid == 0)
    part[P_LOSS + (size_t)t * 96 + snT] =
        (lred[0] + lred[1] + lred[2] + lred[3]) * (1.0f / 3.0f);
  // build A[tap][k=uv]: A = sw^2 * d(y=u+2-ky, x=v+2-kx), zero outside
  for (int idx = tid; idx < 7744; idx += 256) {
    int tap = (unsigned)idx / 484u;
    int k = idx - tap * 484;
    int u = (unsigned)k / 22u, v = k - u * 22;
    int y = u + 2 - (tap >> 2), x = v + 2 - (tap & 3);
    if ((unsigned)y < 23u && (unsigned)x < 23u)
      A_lds[tap * APITCH + k] = (_Float16)(d_arr[y * 23 + x] * (1.0f / 3.0f));
  }
  __syncthreads();
  // GEMM
  int wave = tid >> 6, lane = tid & 63;
  int q = lane >> 4, m16 = lane & 15;
  int ct0 = cg * 8 + wave * 2, ct1 = ct0 + 1;
  f32x4 acc0 = {0.f, 0.f, 0.f, 0.f}, acc1 = {0.f, 0.f, 0.f, 0.f};
  const _Float16* arow = A_lds + m16 * APITCH + q * 8;
  const u16* b0r = featC + ((size_t)snT * 512 + ct0 * 16 + m16) * 512 + q * 8;
  const u16* b1r = featC + ((size_t)snT * 512 + ct1 * 16 + m16) * 512 + q * 8;
#pragma unroll
  for (int step2 = 0; step2 < 16; ++step2) {
    f16x8 a = *(const f16x8*)(arow + step2 * 32);
    f16x8 b0 = *(const f16x8*)(b0r + step2 * 32);
    f16x8 b1 = *(const f16x8*)(b1r + step2 * 32);
    acc0 = __builtin_amdgcn_mfma_f32_16x16x32_f16(a, b0, acc0, 0, 0, 0);
    acc1 = __builtin_amdgcn_mfma_f32_16x16x32_f16(a, b1, acc1, 0, 0, 0);
  }
  // D: col=lane&15 -> c within tile; row=(lane>>4)*4+r -> tap
  float* dgb = dgpart + (size_t)snT * 8192;
#pragma unroll
  for (int r = 0; r < 4; ++r) {
    int tap = q * 4 + r;
    dgb[tap * 512 + ct0 * 16 + m16] = acc0[r];
    dgb[tap * 512 + ct1 * 16 + m16] = acc1[r];
  }
}

// ---------------- weight update: dg = sum_n DGpart + reg*w; wg, wgf16, partials ------
// grid = 32 s x 4 chunks = 128 blocks x 256
__global__ __launch_bounds__(256) void k_wupd(int t, const float* __restrict__ dgpart,
                                              float* __restrict__ wmaster,
                                              float* __restrict__ wg,
                                              u16* __restrict__ wgf16,
                                              float* __restrict__ part,
                                              const float* __restrict__ lsl,
                                              const float* __restrict__ fr) {
  __shared__ float nred[4], wred[4];
  int b = blockIdx.x, tid = threadIdx.x;
  int s = b >> 2, cg = b & 3;
  float step = __expf(lsl[0]);
  float frv = fr[0];
  float reg = fmaxf(frv * frv, 1e-6f);
  float alpha_p = (t >= 1) ? alphaFor(part, t - 1, s, reg) : 0.f;
  const float* d0 = dgpart + (size_t)(s * 3 + 0) * 8192;
  const float* d1 = dgpart + (size_t)(s * 3 + 1) * 8192;
  const float* d2 = dgpart + (size_t)(s * 3 + 2) * 8192;
  float num = 0.f, wsq = 0.f;
  for (int jj = 0; jj < 8; ++jj) {
    int j = cg * 2048 + jj * 256 + tid;
    int tap = j >> 9, c = j & 511;
    float dg = d0[j] + d1[j] + d2[j];
    size_t widx = (size_t)s * 8192 + (size_t)c * 16 + tap;
    float wold = wmaster[widx];
    float wnew = wold;
    if (t >= 1) {  // deferred weight update from previous iteration
      wnew = wold - step * alpha_p * wg[widx];
      wmaster[widx] = wnew;
    }
    float wgn = dg + reg * wnew;
    wg[widx] = wgn;
    wgf16[(size_t)s * 8192 + j] = __half_as_ushort(__float2half(wgn));
    wsq += wnew * wnew;
    num += wgn * wgn;
  }
  num = waveSum(num);
  wsq = waveSum(wsq);
  if ((tid & 63) == 0) {
    nred[tid >> 6] = num;
    wred[tid >> 6] = wsq;
  }
  __syncthreads();
  if (tid == 0) {
    part[P_NUM + (size_t)(t * NS + s) * 4 + cg] = nred[0] + nred[1] + nred[2] + nred[3];
    if (t >= 1)
      part[P_WSQA + (size_t)((t - 1) * NS + s) * 4 + cg] =
          wred[0] + wred[1] + wred[2] + wred[3];
  }
}

// ---------------- final: w5 update + final residual loss parts ----------------
__global__ void k_final(float* __restrict__ wmaster, const float* __restrict__ wg,
                        const float* __restrict__ scores4, const float* __restrict__ sgraw,
                        const float* __restrict__ label, float* __restrict__ part,
                        const float* __restrict__ lsl, const float* __restrict__ fr) {
  __shared__ float alpha_s[32];
  __shared__ float red4[4];
  int b = blockIdx.x, tid = threadIdx.x;
  float step = __expf(lsl[0]);
  float frv = fr[0];
  float reg = fmaxf(frv * frv, 1e-6f);
  if (tid < 32) alpha_s[tid] = alphaFor(part, 4, tid, reg);
  __syncthreads();
  if (b < 1024) {
    int idx = b * 256 + tid;  // 1024*256 == 262144 exactly
    int s = idx >> 13;        // uniform per block
    float w5 = wmaster[idx] - step * alpha_s[s] * wg[idx];
    wmaster[idx] = w5;
    float sq = waveSum(w5 * w5);
    if ((tid & 63) == 0) red4[tid >> 6] = sq;
    __syncthreads();
    if (tid == 0) part[P_WSQ5 + b] = red4[0] + red4[1] + red4[2] + red4[3];
  } else {
    int p = (b - 1024) * 256 + tid;
    float contrib = 0.f;
    if (p < NP) {
      int nsid = p / P2;
      int s = nsid & 31;  // nsid = n*NS + s
      float s5 = scores4[p] - step * alpha_s[s] * sgraw[p];
      float d = s5 - label[p];
      contrib = d * d;
    }
    contrib = waveSum(contrib);
    if ((tid & 63) == 0) red4[tid >> 6] = contrib;
    __syncthreads();
    if (tid == 0)
      part[P_L5 + (b - 1024)] = (red4[0] + red4[1] + red4[2] + red4[3]) * (1.0f / 3.0f);
  }
}

// ---------------- losses: deterministic sums of all partials ----------------
__global__ void k_losses(float* __restrict__ out_losses, const float* __restrict__ part,
                         const float* __restrict__ fr) {
  __shared__ float red[8];
  int tid = threadIdx.x;  // 256
  float frv = fr[0];
  float reg = fmaxf(frv * frv, 1e-6f);
  float v5 = 0.f;
  for (int i = tid; i < 1024; i += 256) v5 += part[P_WSQ5 + i];
  v5 = waveSum(v5);
  if ((tid & 63) == 0) red[tid >> 6] = v5;
  __syncthreads();
  float wsq5 = red[0] + red[1] + red[2] + red[3];
  float l5 = 0.f;
  for (int i = tid; i < 199; i += 256) l5 += part[P_L5 + i];
  l5 = waveSum(l5);
  if ((tid & 63) == 0) red[4 + (tid >> 6)] = l5;
  __syncthreads();
  float loss5 = red[4] + red[5] + red[6] + red[7];
  if (tid < 5) {
    int t = tid;
    float ls = 0.f;
    for (int i = 0; i < 96; ++i) ls += part[P_LOSS + t * 96 + i];
    float ws_ = 0.f;
    if (t == 0) {
      for (int i = 0; i < 32; ++i) ws_ += part[P_WSQ0 + i];
    } else {
      for (int i = 0; i < 128; ++i) ws_ += part[P_WSQA + (t - 1) * 128 + i];
    }
    out_losses[t] = (ls + reg * ws_) * (1.0f / 32.0f);
  }
  if (tid == 5) out_losses[5] = (loss5 + reg * wsq5) * (1.0f / 32.0f);
}

// ---------------- launch ----------------
extern "C" void kernel_launch(void* const* d_in, const int* in_sizes, int n_in,
                              void* d_out, int out_size, void* d_ws, size_t ws_size,
                              hipStream_t stream) {
  const float* w0 = (const float*)d_in[0];
  const float* feat = (const float*)d_in[1];
  const float* bb = (const float*)d_in[2];
  const float* lsl = (const float*)d_in[3];
  const float* fr = (const float*)d_in[4];
  float* out = (float*)d_out;
  char* ws = (char*)d_ws;
  u16* featT = (u16*)(ws + OFF_FEATT);
  u16* featC = (u16*)(ws + OFF_FEATC);
  float* label = (float*)(ws + OFF_LABEL);
  float* s0 = (float*)(ws + OFF_S0);
  float* s1 = (float*)(ws + OFF_S1);
  float* sgraw = (float*)(ws + OFF_SGRAW);
  float* wg = (float*)(ws + OFF_WG);
  u16* wgf16 = (u16*)(ws + OFF_WGF16);
  u16* w0f16 = (u16*)(ws + OFF_W0F16);
  float* dgpart = (float*)(ws + OFF_DG);
  float* gbuf = (float*)(ws + OFF_GBUF);
  float* part = (float*)(ws + OFF_PART);

  k_setup<<<7911, 256, 0, stream>>>(feat, w0, bb, featT, featC, w0f16, out, label, part);
  // initial scores_0 = A * w0
  k_conv_gemm<<<384, 256, 0, stream>>>(featT, w0f16, gbuf);
  k_gather<<<96, 256, 0, stream>>>(gbuf, s0, -1, part);
  float* sbuf[2] = {s0, s1};
  for (int t = 0; t < 5; ++t) {
    const float* so = (t == 0) ? s0 : sbuf[(t - 1) & 1];
    float* sn = sbuf[t & 1];
    k_adjoint_gemm<<<384, 256, 0, stream>>>(t, featC, label, so, sn, sgraw, dgpart, part,
                                            lsl, fr);
    k_wupd<<<128, 256, 0, stream>>>(t, dgpart, out, wg, wgf16, part, lsl, fr);
    k_conv_gemm<<<384, 256, 0, stream>>>(featT, wgf16, gbuf);
    k_gather<<<96, 256, 0, stream>>>(gbuf, sgraw, t, part);
  }
  // scores_4 lives in s0 after t=4
  k_final<<<1223, 256, 0, stream>>>(out, wg, s0, sgraw, label, part, lsl, fr);
  k_losses<<<1, 256, 0, stream>>>(out + WSZ, part, fr);
}